// Round 9
// baseline (582.943 us; speedup 1.0000x reference)
//
#include <hip/hip_runtime.h>
#include <hip/hip_bf16.h>
#include <stdint.h>

typedef __attribute__((ext_vector_type(8))) __bf16 bf16x8;
typedef __attribute__((ext_vector_type(4))) __bf16 bf16x4;
typedef __attribute__((ext_vector_type(4))) float  f32x4;

#define NTOK   8192
#define DMODEL 1024
#define HDIM   4096
#define NEXP   8

__device__ __forceinline__ void glds16(const void* g, void* l) {
  __builtin_amdgcn_global_load_lds(
      (const __attribute__((address_space(1))) uint32_t*)g,
      (__attribute__((address_space(3))) uint32_t*)l, 16, 0, 0);
}

#define WAITV(N) asm volatile("s_waitcnt vmcnt(" #N ")" ::: "memory")
#define SBAR()  do { __builtin_amdgcn_sched_barrier(0); \
                     __builtin_amdgcn_s_barrier();      \
                     __builtin_amdgcn_sched_barrier(0); } while (0)

// ------------------------------------------------------------------ utils
__global__ void zero_cnt_kernel(int* cnt) {
  if (threadIdx.x < NEXP) cnt[threadIdx.x] = 0;
}

// base[e+1] = base[e] + round256(cnt[e])   (256-row M-tiles)
__global__ void prefix_kernel(const int* __restrict__ cnt, int* __restrict__ base) {
  if (threadIdx.x == 0) {
    int b = 0;
    base[0] = 0;
    for (int e = 0; e < NEXP; ++e) {
      b += (cnt[e] + 255) & ~255;
      base[e + 1] = b;
    }
  }
}

// zero out (atomicAdd target for split-K GEMM2; out not re-poisoned between
// replays, so this must run every call)
__global__ __launch_bounds__(256) void zero_out_kernel(float* __restrict__ out) {
  float4 z = {0.f, 0.f, 0.f, 0.f};
  float4* p = (float4*)out + (size_t)blockIdx.x * 1024 + threadIdx.x;
#pragma unroll
  for (int i = 0; i < 4; ++i) p[i * 256] = z;
}

// ------------------------------------------------------------------ gating
__global__ __launch_bounds__(256) void moe_gate_kernel(
    const float* __restrict__ x, const float* __restrict__ gw,
    const float* __restrict__ gb, float* __restrict__ wgt,
    int* __restrict__ cnt, int* __restrict__ meta)
{
  const int lane = threadIdx.x & 63;
  const int wv   = threadIdx.x >> 6;
  const int t    = (blockIdx.x << 2) + wv;
  const float* xp = x + (size_t)t * DMODEL;

  float acc[NEXP];
#pragma unroll
  for (int e = 0; e < NEXP; ++e) acc[e] = 0.f;

#pragma unroll
  for (int j = 0; j < DMODEL / 64; ++j) {
    const int d = (j << 6) + lane;
    const float xv = xp[d];
    const float4 g0 = *(const float4*)(gw + (size_t)d * NEXP);
    const float4 g1 = *(const float4*)(gw + (size_t)d * NEXP + 4);
    acc[0] = fmaf(xv, g0.x, acc[0]);
    acc[1] = fmaf(xv, g0.y, acc[1]);
    acc[2] = fmaf(xv, g0.z, acc[2]);
    acc[3] = fmaf(xv, g0.w, acc[3]);
    acc[4] = fmaf(xv, g1.x, acc[4]);
    acc[5] = fmaf(xv, g1.y, acc[5]);
    acc[6] = fmaf(xv, g1.z, acc[6]);
    acc[7] = fmaf(xv, g1.w, acc[7]);
  }
#pragma unroll
  for (int e = 0; e < NEXP; ++e) {
#pragma unroll
    for (int off = 32; off > 0; off >>= 1)
      acc[e] += __shfl_xor(acc[e], off, 64);
  }
  if (lane == 0) {
    float l[NEXP];
#pragma unroll
    for (int e = 0; e < NEXP; ++e) l[e] = acc[e] + gb[e];
    int i1 = 0; float m1 = l[0];
#pragma unroll
    for (int e = 1; e < NEXP; ++e) if (l[e] > m1) { m1 = l[e]; i1 = e; }
    int i2 = -1; float m2 = -3.402823466e38f;
#pragma unroll
    for (int e = 0; e < NEXP; ++e) if (e != i1 && l[e] > m2) { m2 = l[e]; i2 = e; }
    const int es = i1 > i2 ? i1 : i2;   // reference: last expert in loop wins
    float s = 0.f;
#pragma unroll
    for (int e = 0; e < NEXP; ++e) s += expf(l[e] - m1);
    const float w = expf(l[es] - m1) / s;
    wgt[t] = w;
    const int pos = atomicAdd(&cnt[es], 1);
    meta[t] = (es << 13) | pos;
  }
}

// -------------------------------------------------- pack x (sorted order)
// No zeropad kernel: pad rows keep stale 0xAA (= -3e-13 bf16, harmless);
// GEMM1 writes 0 to hmat pad rows; GEMM2 scatters only gm<ce rows.
__global__ __launch_bounds__(256) void pack_x_kernel(
    const float* __restrict__ x, const float* __restrict__ wgt,
    const int* __restrict__ meta, const int* __restrict__ base,
    __bf16* __restrict__ xbf, int* __restrict__ sortmap)
{
  const int t = blockIdx.x * 2 + (threadIdx.x >> 7);
  const int l = threadIdx.x & 127;
  const int m = meta[t];
  const int es = m >> 13, pos = m & 8191;
  const int dst = base[es] + pos;
  const float w = wgt[t];
  const float4 a = *(const float4*)(x + (size_t)t * DMODEL + l * 8);
  const float4 b = *(const float4*)(x + (size_t)t * DMODEL + l * 8 + 4);
  bf16x8 o;
  o[0] = (__bf16)(a.x * w); o[1] = (__bf16)(a.y * w);
  o[2] = (__bf16)(a.z * w); o[3] = (__bf16)(a.w * w);
  o[4] = (__bf16)(b.x * w); o[5] = (__bf16)(b.y * w);
  o[6] = (__bf16)(b.z * w); o[7] = (__bf16)(b.w * w);
  *(bf16x8*)(xbf + (size_t)dst * DMODEL + l * 8) = o;
  if (l == 0) sortmap[dst] = t;
}

// ------------------------------------------------------------------ pack W
// Transpose src [E][K][N] fp32 -> dst [E][N/128][128 n][K] bf16 (k-contig
// rows; GEMM applies the LDS swizzle at glds-source time).
template<int N, int K>
__global__ __launch_bounds__(256) void pack_w_kernel(
    const float* __restrict__ src, __bf16* __restrict__ dst)
{
  const int k0 = blockIdx.x * 64, np = blockIdx.y, e = blockIdx.z;
  const int t = threadIdx.x;
  __shared__ __bf16 sh[8192];   // 64 k x 128 n, n4 XOR-swizzled by (k&3)

  const float* sp = src + (size_t)e * K * N + (size_t)k0 * N + np * 128;
#pragma unroll
  for (int i = 0; i < 8; ++i) {
    const int id = i * 256 + t;
    const int k = id >> 5, n4 = id & 31;
    const float4 v = *(const float4*)(sp + (size_t)k * N + n4 * 4);
    const int phys = n4 ^ ((k & 3) << 3);
    bf16x4 o; o[0] = (__bf16)v.x; o[1] = (__bf16)v.y;
              o[2] = (__bf16)v.z; o[3] = (__bf16)v.w;
    *(bf16x4*)&sh[k * 128 + phys * 4] = o;
  }
  __syncthreads();

  __bf16* dbase = dst + ((size_t)(e * (N / 128) + np) * 128) * K + k0;
#pragma unroll
  for (int j2 = 0; j2 < 4; ++j2) {
    const int c = j2 * 256 + t;
    const int n = c >> 3, ks8 = c & 7;
    bf16x8 v;
#pragma unroll
    for (int j = 0; j < 8; ++j) {
      const int k = ks8 * 8 + j;
      v[j] = sh[k * 128 + (((n >> 2) ^ ((k & 3) << 3)) << 2) + (n & 3)];
    }
    *(bf16x8*)(dbase + (size_t)n * K + ks8 * 8) = v;
  }
}

// ------------------------------------------------------------------ GEMM
// r7 body (proven correct, 0 bank conflicts): 256x256 tile, 8 waves
// (2M x 4N, wave tile 128x64), BK=64, 2-buffer LDS (128KB), vmcnt(0) +
// 1 barrier pair per K-tile. LDS rows 128B, granule phys = q ^ (row&7),
// swizzle applied at glds SOURCE (wave-uniform linear dest, m104 rule).
// NEW: 1D grid with expert->XCD pinning (e = id&7; np-outer, m-inner within
// the XCD so A-tiles and the current B-panel stay L2-resident), and
// optional split-K (SPLITK=2): each half computes K/2 and atomicAdds into a
// pre-zeroed fp32 out; bias added by the kh==0 half only.
template<int KSTEPS, int SPLITK, int ASTRIDE, int NOUT, bool RELU, bool SCATTER, typename OutT>
__global__ __launch_bounds__(512, 1) void moe_gemm256_kernel(
    const __bf16* __restrict__ Am, const __bf16* __restrict__ Bp,
    const float* __restrict__ bias, const int* __restrict__ cnt,
    const int* __restrict__ base, const int* __restrict__ sortmap,
    OutT* __restrict__ outp)
{
  // ---- grid decode: id = (slot<<3)|e ; slot = np*(40*SPLITK) + kh*40 + m
  const int id = blockIdx.x;
  const int e  = id & 7;
  const int slot = id >> 3;
  const int np = slot / (40 * SPLITK);
  const int kh = (SPLITK > 1) ? ((slot / 40) % SPLITK) : 0;
  const int m  = slot % 40;

  const int ce = cnt[e];
  const int rb = base[e];
  const int cep = base[e + 1] - rb;        // padded count (multiple of 256)
  const int m0 = m << 8;
  if (m0 >= cep) return;
  const int n0 = np << 8;

  constexpr int KH = KSTEPS / SPLITK;
  const int kbase = kh * KH;

  const int tid = threadIdx.x, lane = tid & 63, wv = tid >> 6;
  const int wm = wv >> 2, wn = wv & 3;     // wave tile: rows wm*128, cols wn*64
  const int rl = lane & 15, sl = lane >> 4;

  __shared__ alignas(16) __bf16 lds[65536];   // 2 buffers x 64KB

  // per-lane staging SOURCES: 4 A + 4 B chunks (16B) per K-tile
  const __bf16* asrc[4];
  const __bf16* bsrc[4];
#pragma unroll
  for (int i = 0; i < 4; ++i) {
    const int c = (wv * 4 + i) * 64 + lane;       // chunk id 0..2047
    const int r = c >> 3, p = c & 7;              // tile row 0..255, granule
    const int koff = (p ^ (r & 7)) * 8 + kbase * 64;
    asrc[i] = Am + (size_t)(rb + m0 + r) * ASTRIDE + koff;
    bsrc[i] = Bp + ((size_t)(e * (NOUT / 128) + np * 2) * 128 + r) * ASTRIDE + koff;
  }

  auto stage = [&](int buf, int ks) {
    __bf16* Ad = lds + buf * 32768;               // wave-uniform dests
    __bf16* Bd = Ad + 16384;
#pragma unroll
    for (int i = 0; i < 4; ++i)
      glds16(asrc[i] + ks * 64, Ad + (wv * 4 + i) * 512);
#pragma unroll
    for (int i = 0; i < 4; ++i)
      glds16(bsrc[i] + ks * 64, Bd + (wv * 4 + i) * 512);
  };

  f32x4 acc[8][4] = {};

  stage(0, 0);
  for (int ks = 0; ks < KH; ++ks) {
    const int buf = ks & 1;
    WAITV(0);                    // this K-tile's stages (issued last iter) landed
    SBAR();                      // visible to all waves; prev buf fully read
    if (ks + 1 < KH) stage(buf ^ 1, ks + 1);

    const char* Ab = (const char*)lds + buf * 65536 + wm * 16384;
    const char* Bb = (const char*)lds + buf * 65536 + 32768 + (wn >> 1) * 16384;

#pragma unroll
    for (int kk = 0; kk < 2; ++kk) {
      bf16x8 af[8];
#pragma unroll
      for (int mf = 0; mf < 8; ++mf) {
        const int row = mf * 16 + rl;
        af[mf] = *(const bf16x8*)(Ab + row * 128 + (((kk * 4 + sl) ^ (row & 7)) << 4));
      }
#pragma unroll
      for (int nh = 0; nh < 2; ++nh) {
        bf16x8 bf[2];
#pragma unroll
        for (int nf2 = 0; nf2 < 2; ++nf2) {
          const int row = (wn & 1) * 64 + nh * 32 + nf2 * 16 + rl;
          bf[nf2] = *(const bf16x8*)(Bb + row * 128 + (((kk * 4 + sl) ^ (row & 7)) << 4));
        }
        __builtin_amdgcn_s_setprio(1);
#pragma unroll
        for (int mf = 0; mf < 8; ++mf)
#pragma unroll
          for (int nf2 = 0; nf2 < 2; ++nf2)
            acc[mf][nh * 2 + nf2] = __builtin_amdgcn_mfma_f32_16x16x32_bf16(
                af[mf], bf[nf2], acc[mf][nh * 2 + nf2], 0, 0, 0);
        __builtin_amdgcn_s_setprio(0);
      }
    }
  }

  // epilogue
  const int cl = rl;
  float bb[4];
#pragma unroll
  for (int nf = 0; nf < 4; ++nf)
    bb[nf] = bias[(size_t)e * NOUT + n0 + wn * 64 + nf * 16 + cl];

#pragma unroll
  for (int mf = 0; mf < 8; ++mf) {
#pragma unroll
    for (int j = 0; j < 4; ++j) {
      const int gm = m0 + wm * 128 + mf * 16 + sl * 4 + j;
      if constexpr (SCATTER) {
        if (gm < ce) {
          const int tok = sortmap[rb + gm];
          OutT* op = outp + (size_t)tok * NOUT + n0 + wn * 64;
#pragma unroll
          for (int nf = 0; nf < 4; ++nf) {
            float v = acc[mf][nf][j] + ((kh == 0) ? bb[nf] : 0.f);
            if constexpr (SPLITK > 1)
              atomicAdd((float*)&op[nf * 16 + cl], v);
            else
              op[nf * 16 + cl] = (OutT)v;
          }
        }
      } else {
        OutT* op = outp + (size_t)(rb + gm) * NOUT + n0 + wn * 64;
        const bool live = gm < ce;
#pragma unroll
        for (int nf = 0; nf < 4; ++nf) {
          float v = acc[mf][nf][j] + bb[nf];
          if constexpr (RELU) v = fmaxf(v, 0.f);
          op[nf * 16 + cl] = live ? (OutT)v : (OutT)0.f;
        }
      }
    }
  }
}

// ------------------------------------------------------------------ launch
extern "C" void kernel_launch(void* const* d_in, const int* in_sizes, int n_in,
                              void* d_out, int out_size, void* d_ws, size_t ws_size,
                              hipStream_t stream)
{
  const float* x  = (const float*)d_in[0];
  const float* gw = (const float*)d_in[1];
  const float* gb = (const float*)d_in[2];
  const float* w1 = (const float*)d_in[3];
  const float* b1 = (const float*)d_in[4];
  const float* w2 = (const float*)d_in[5];
  const float* b2 = (const float*)d_in[6];
  float* out = (float*)d_out;

  char* ws = (char*)d_ws;
  int*    cnt     = (int*)ws;                               // 32 B
  int*    base    = (int*)(ws + 256);                       // 9 ints
  int*    meta    = (int*)(ws + 4096);                      // 32 KB
  float*  wgt     = (float*)(ws + 40960);                   // 32 KB
  int*    sortmap = (int*)(ws + 81920);                     // 41 KB
  __bf16* xbf     = (__bf16*)(ws + ((size_t)1   << 20));    // <= 20.5 MB (10240 rows)
  __bf16* hmat    = (__bf16*)(ws + ((size_t)22  << 20));    // <= 80 MB   (10240 rows)
  __bf16* wp      = (__bf16*)(ws + ((size_t)104 << 20));    // 64 MB (w1p then w2p)

  zero_cnt_kernel<<<1, 64, 0, stream>>>(cnt);
  moe_gate_kernel<<<NTOK / 4, 256, 0, stream>>>(x, gw, gb, wgt, cnt, meta);
  prefix_kernel<<<1, 64, 0, stream>>>(cnt, base);
  pack_x_kernel<<<NTOK / 2, 256, 0, stream>>>(x, wgt, meta, base, xbf, sortmap);
  zero_out_kernel<<<NTOK / 4, 256, 0, stream>>>(out);       // split-K target

  // GEMM1: grid = 16 np x 40 m x 8 e, expert-pinned to XCD (e = id&7)
  pack_w_kernel<HDIM, DMODEL><<<dim3(DMODEL / 64, HDIM / 128, NEXP), 256, 0, stream>>>(w1, wp);
  moe_gemm256_kernel<DMODEL / 64, 1, DMODEL, HDIM, true, false, __bf16>
      <<<(HDIM / 256) * 40 * NEXP, 512, 0, stream>>>(
          xbf, wp, b1, cnt, base, sortmap, hmat);

  // GEMM2: split-K=2, grid = 4 np x 2 kh x 40 m x 8 e
  pack_w_kernel<DMODEL, HDIM><<<dim3(HDIM / 64, DMODEL / 128, NEXP), 256, 0, stream>>>(w2, wp);
  moe_gemm256_kernel<HDIM / 64, 2, HDIM, DMODEL, false, true, float>
      <<<(DMODEL / 256) * 2 * 40 * NEXP, 512, 0, stream>>>(
          hmat, wp, b2, cnt, base, sortmap, out);
}

// Round 10
// 510.057 us; speedup vs baseline: 1.1429x; 1.1429x over previous
//
#include <hip/hip_runtime.h>
#include <hip/hip_bf16.h>
#include <stdint.h>

typedef __attribute__((ext_vector_type(8))) __bf16 bf16x8;
typedef __attribute__((ext_vector_type(4))) __bf16 bf16x4;
typedef __attribute__((ext_vector_type(4))) float  f32x4;

#define NTOK   8192
#define DMODEL 1024
#define HDIM   4096
#define NEXP   8

__device__ __forceinline__ void glds16(const void* g, void* l) {
  __builtin_amdgcn_global_load_lds(
      (const __attribute__((address_space(1))) uint32_t*)g,
      (__attribute__((address_space(3))) uint32_t*)l, 16, 0, 0);
}

#define WAITV(N) asm volatile("s_waitcnt vmcnt(" #N ")" ::: "memory")
#define SBAR()  do { __builtin_amdgcn_sched_barrier(0); \
                     __builtin_amdgcn_s_barrier();      \
                     __builtin_amdgcn_sched_barrier(0); } while (0)

// ------------------------------------------------------------------ utils
__global__ void zero_cnt_kernel(int* cnt) {
  if (threadIdx.x < NEXP) cnt[threadIdx.x] = 0;
}

// base[e+1] = base[e] + round256(cnt[e])   (256-row M-tiles)
__global__ void prefix_kernel(const int* __restrict__ cnt, int* __restrict__ base) {
  if (threadIdx.x == 0) {
    int b = 0;
    base[0] = 0;
    for (int e = 0; e < NEXP; ++e) {
      b += (cnt[e] + 255) & ~255;
      base[e + 1] = b;
    }
  }
}

// zero out (atomicAdd target for split-K GEMM2; must run every call since
// the harness does not re-poison between replays)
__global__ __launch_bounds__(256) void zero_out_kernel(float* __restrict__ out) {
  float4 z = {0.f, 0.f, 0.f, 0.f};
  float4* p = (float4*)out + (size_t)blockIdx.x * 1024 + threadIdx.x;
#pragma unroll
  for (int i = 0; i < 4; ++i) p[i * 256] = z;
}

// ------------------------------------------------------------------ gating
__global__ __launch_bounds__(256) void moe_gate_kernel(
    const float* __restrict__ x, const float* __restrict__ gw,
    const float* __restrict__ gb, float* __restrict__ wgt,
    int* __restrict__ cnt, int* __restrict__ meta)
{
  const int lane = threadIdx.x & 63;
  const int wv   = threadIdx.x >> 6;
  const int t    = (blockIdx.x << 2) + wv;
  const float* xp = x + (size_t)t * DMODEL;

  float acc[NEXP];
#pragma unroll
  for (int e = 0; e < NEXP; ++e) acc[e] = 0.f;

#pragma unroll
  for (int j = 0; j < DMODEL / 64; ++j) {
    const int d = (j << 6) + lane;
    const float xv = xp[d];
    const float4 g0 = *(const float4*)(gw + (size_t)d * NEXP);
    const float4 g1 = *(const float4*)(gw + (size_t)d * NEXP + 4);
    acc[0] = fmaf(xv, g0.x, acc[0]);
    acc[1] = fmaf(xv, g0.y, acc[1]);
    acc[2] = fmaf(xv, g0.z, acc[2]);
    acc[3] = fmaf(xv, g0.w, acc[3]);
    acc[4] = fmaf(xv, g1.x, acc[4]);
    acc[5] = fmaf(xv, g1.y, acc[5]);
    acc[6] = fmaf(xv, g1.z, acc[6]);
    acc[7] = fmaf(xv, g1.w, acc[7]);
  }
#pragma unroll
  for (int e = 0; e < NEXP; ++e) {
#pragma unroll
    for (int off = 32; off > 0; off >>= 1)
      acc[e] += __shfl_xor(acc[e], off, 64);
  }
  if (lane == 0) {
    float l[NEXP];
#pragma unroll
    for (int e = 0; e < NEXP; ++e) l[e] = acc[e] + gb[e];
    int i1 = 0; float m1 = l[0];
#pragma unroll
    for (int e = 1; e < NEXP; ++e) if (l[e] > m1) { m1 = l[e]; i1 = e; }
    int i2 = -1; float m2 = -3.402823466e38f;
#pragma unroll
    for (int e = 0; e < NEXP; ++e) if (e != i1 && l[e] > m2) { m2 = l[e]; i2 = e; }
    const int es = i1 > i2 ? i1 : i2;   // reference: last expert in loop wins
    float s = 0.f;
#pragma unroll
    for (int e = 0; e < NEXP; ++e) s += expf(l[e] - m1);
    const float w = expf(l[es] - m1) / s;
    wgt[t] = w;
    const int pos = atomicAdd(&cnt[es], 1);
    meta[t] = (es << 13) | pos;
  }
}

// -------------------------------------------------- pack x (sorted order)
// Pad rows keep stale bytes (finite bf16, harmless): GEMM1 writes 0 to hmat
// pad rows; GEMM2 only scatters gm<ce rows.
__global__ __launch_bounds__(256) void pack_x_kernel(
    const float* __restrict__ x, const float* __restrict__ wgt,
    const int* __restrict__ meta, const int* __restrict__ base,
    __bf16* __restrict__ xbf, int* __restrict__ sortmap)
{
  const int t = blockIdx.x * 2 + (threadIdx.x >> 7);
  const int l = threadIdx.x & 127;
  const int m = meta[t];
  const int es = m >> 13, pos = m & 8191;
  const int dst = base[es] + pos;
  const float w = wgt[t];
  const float4 a = *(const float4*)(x + (size_t)t * DMODEL + l * 8);
  const float4 b = *(const float4*)(x + (size_t)t * DMODEL + l * 8 + 4);
  bf16x8 o;
  o[0] = (__bf16)(a.x * w); o[1] = (__bf16)(a.y * w);
  o[2] = (__bf16)(a.z * w); o[3] = (__bf16)(a.w * w);
  o[4] = (__bf16)(b.x * w); o[5] = (__bf16)(b.y * w);
  o[6] = (__bf16)(b.z * w); o[7] = (__bf16)(b.w * w);
  *(bf16x8*)(xbf + (size_t)dst * DMODEL + l * 8) = o;
  if (l == 0) sortmap[dst] = t;
}

// ------------------------------------------------------------------ pack W
// Transpose src [E][K][N] fp32 -> dst [E][N/128][128 n][K] bf16 (k-contig
// rows; GEMM applies the LDS swizzle at glds-source time).
template<int N, int K>
__global__ __launch_bounds__(256) void pack_w_kernel(
    const float* __restrict__ src, __bf16* __restrict__ dst)
{
  const int k0 = blockIdx.x * 64, np = blockIdx.y, e = blockIdx.z;
  const int t = threadIdx.x;
  __shared__ __bf16 sh[8192];   // 64 k x 128 n, n4 XOR-swizzled by (k&3)

  const float* sp = src + (size_t)e * K * N + (size_t)k0 * N + np * 128;
#pragma unroll
  for (int i = 0; i < 8; ++i) {
    const int id = i * 256 + t;
    const int k = id >> 5, n4 = id & 31;
    const float4 v = *(const float4*)(sp + (size_t)k * N + n4 * 4);
    const int phys = n4 ^ ((k & 3) << 3);
    bf16x4 o; o[0] = (__bf16)v.x; o[1] = (__bf16)v.y;
              o[2] = (__bf16)v.z; o[3] = (__bf16)v.w;
    *(bf16x4*)&sh[k * 128 + phys * 4] = o;
  }
  __syncthreads();

  __bf16* dbase = dst + ((size_t)(e * (N / 128) + np) * 128) * K + k0;
#pragma unroll
  for (int j2 = 0; j2 < 4; ++j2) {
    const int c = j2 * 256 + t;
    const int n = c >> 3, ks8 = c & 7;
    bf16x8 v;
#pragma unroll
    for (int j = 0; j < 8; ++j) {
      const int k = ks8 * 8 + j;
      v[j] = sh[k * 128 + (((n >> 2) ^ ((k & 3) << 3)) << 2) + (n & 3)];
    }
    *(bf16x8*)(dbase + (size_t)n * K + ks8 * 8) = v;
  }
}

// ------------------------------------------------------------------ GEMM
// 256x256 tile, *16 waves* (4M x 4N, wave tile 64x64), BK=64, 2-buffer LDS
// (128KB), r7's verified schedule: per K-tile { WAITV(0); barrier; stage
// next tile into other buffer; compute }. LDS rows 128B, granule phys =
// q ^ (row&7), swizzle at glds SOURCE (wave-uniform linear dest, m104 rule).
// 16 waves -> 4 waves/SIMD (vs r7's 2): 4 independent MFMA streams per SIMD
// fill the matrix pipe and hide ds_read issue. launch_bounds(1024,4) caps
// VGPR at 128 (acc 64 + frags ~24 + addr ~25 fits).
// Split-K (GEMM2): kh = blockIdx.y/40, partials atomicAdd into zeroed out,
// bias added by kh==0 only (r9-verified path).
template<int KSTEPS, int SPLITK, int ASTRIDE, int NOUT, bool RELU, bool SCATTER, typename OutT>
__global__ __launch_bounds__(1024, 4) void moe_gemm256_kernel(
    const __bf16* __restrict__ Am, const __bf16* __restrict__ Bp,
    const float* __restrict__ bias, const int* __restrict__ cnt,
    const int* __restrict__ base, const int* __restrict__ sortmap,
    OutT* __restrict__ outp)
{
  const int e  = blockIdx.z;
  const int ce = cnt[e];
  const int rb = base[e];
  const int cep = base[e + 1] - rb;        // padded count (multiple of 256)
  const int m  = blockIdx.y % 40;
  const int kh = blockIdx.y / 40;
  const int m0 = m << 8;
  if (m0 >= cep) return;
  const int np = blockIdx.x, n0 = np << 8;

  constexpr int KH = KSTEPS / SPLITK;
  const int kbase = kh * KH * 64;          // element offset of this K-chunk

  const int tid = threadIdx.x, lane = tid & 63, wv = tid >> 6;  // wv 0..15
  const int wm = wv >> 2, wn = wv & 3;     // wave tile: rows wm*64, cols wn*64
  const int rl = lane & 15, sl = lane >> 4;

  __shared__ alignas(16) __bf16 lds[65536];   // 2 buffers x 64KB

  // per-lane staging SOURCES: 2 A + 2 B chunks (16B) per K-tile
  const __bf16* asrc[2];
  const __bf16* bsrc[2];
#pragma unroll
  for (int i = 0; i < 2; ++i) {
    const int c = (wv * 2 + i) * 64 + lane;       // chunk id 0..2047
    const int r = c >> 3, p = c & 7;              // tile row 0..255, granule
    const int koff = (p ^ (r & 7)) * 8 + kbase;
    asrc[i] = Am + (size_t)(rb + m0 + r) * ASTRIDE + koff;
    bsrc[i] = Bp + ((size_t)(e * (NOUT / 128) + np * 2) * 128 + r) * ASTRIDE + koff;
  }

  auto stage = [&](int buf, int ks) {
    __bf16* Ad = lds + buf * 32768;               // wave-uniform dests
    __bf16* Bd = Ad + 16384;
#pragma unroll
    for (int i = 0; i < 2; ++i)
      glds16(asrc[i] + ks * 64, Ad + (wv * 2 + i) * 512);
#pragma unroll
    for (int i = 0; i < 2; ++i)
      glds16(bsrc[i] + ks * 64, Bd + (wv * 2 + i) * 512);
  };

  f32x4 acc[4][4] = {};

  stage(0, 0);
  for (int ks = 0; ks < KH; ++ks) {
    const int buf = ks & 1;
    WAITV(0);                    // this K-tile's stages (issued last iter) landed
    SBAR();                      // visible to all waves; prev buf fully read
    if (ks + 1 < KH) stage(buf ^ 1, ks + 1);

    const char* Ab = (const char*)lds + buf * 65536;
    const char* Bb = Ab + 32768;

#pragma unroll
    for (int kk = 0; kk < 2; ++kk) {
      bf16x8 af[4];
#pragma unroll
      for (int mf = 0; mf < 4; ++mf) {
        const int row = wm * 64 + mf * 16 + rl;
        af[mf] = *(const bf16x8*)(Ab + row * 128 + (((kk * 4 + sl) ^ (row & 7)) << 4));
      }
#pragma unroll
      for (int nh = 0; nh < 2; ++nh) {
        bf16x8 bf2[2];
#pragma unroll
        for (int f = 0; f < 2; ++f) {
          const int row = wn * 64 + (nh * 2 + f) * 16 + rl;
          bf2[f] = *(const bf16x8*)(Bb + row * 128 + (((kk * 4 + sl) ^ (row & 7)) << 4));
        }
        __builtin_amdgcn_s_setprio(1);
#pragma unroll
        for (int mf = 0; mf < 4; ++mf)
#pragma unroll
          for (int f = 0; f < 2; ++f)
            acc[mf][nh * 2 + f] = __builtin_amdgcn_mfma_f32_16x16x32_bf16(
                af[mf], bf2[f], acc[mf][nh * 2 + f], 0, 0, 0);
        __builtin_amdgcn_s_setprio(0);
      }
    }
  }

  // epilogue: bias (+relu); sorted write, or token scatter (+split-K atomic)
  float bb[4];
#pragma unroll
  for (int nf = 0; nf < 4; ++nf)
    bb[nf] = bias[(size_t)e * NOUT + n0 + wn * 64 + nf * 16 + rl];

#pragma unroll
  for (int mf = 0; mf < 4; ++mf) {
#pragma unroll
    for (int j = 0; j < 4; ++j) {
      const int gm = m0 + wm * 64 + mf * 16 + sl * 4 + j;
      if constexpr (SCATTER) {
        if (gm < ce) {
          const int tok = sortmap[rb + gm];
          OutT* op = outp + (size_t)tok * NOUT + n0 + wn * 64;
#pragma unroll
          for (int nf = 0; nf < 4; ++nf) {
            float v = acc[mf][nf][j] + ((kh == 0) ? bb[nf] : 0.f);
            if constexpr (SPLITK > 1)
              atomicAdd((float*)&op[nf * 16 + rl], v);
            else
              op[nf * 16 + rl] = (OutT)v;
          }
        }
      } else {
        OutT* op = outp + (size_t)(rb + gm) * NOUT + n0 + wn * 64;
        const bool live = gm < ce;
#pragma unroll
        for (int nf = 0; nf < 4; ++nf) {
          float v = acc[mf][nf][j] + bb[nf];
          if constexpr (RELU) v = fmaxf(v, 0.f);
          op[nf * 16 + rl] = live ? (OutT)v : (OutT)0.f;
        }
      }
    }
  }
}

// ------------------------------------------------------------------ launch
extern "C" void kernel_launch(void* const* d_in, const int* in_sizes, int n_in,
                              void* d_out, int out_size, void* d_ws, size_t ws_size,
                              hipStream_t stream)
{
  const float* x  = (const float*)d_in[0];
  const float* gw = (const float*)d_in[1];
  const float* gb = (const float*)d_in[2];
  const float* w1 = (const float*)d_in[3];
  const float* b1 = (const float*)d_in[4];
  const float* w2 = (const float*)d_in[5];
  const float* b2 = (const float*)d_in[6];
  float* out = (float*)d_out;

  char* ws = (char*)d_ws;
  int*    cnt     = (int*)ws;                               // 32 B
  int*    base    = (int*)(ws + 256);                       // 9 ints
  int*    meta    = (int*)(ws + 4096);                      // 32 KB
  float*  wgt     = (float*)(ws + 40960);                   // 32 KB
  int*    sortmap = (int*)(ws + 81920);                     // 41 KB
  __bf16* xbf     = (__bf16*)(ws + ((size_t)1   << 20));    // <= 20.5 MB (10240 rows)
  __bf16* hmat    = (__bf16*)(ws + ((size_t)22  << 20));    // <= 80 MB   (10240 rows)
  __bf16* wp      = (__bf16*)(ws + ((size_t)104 << 20));    // 64 MB (w1p then w2p)

  zero_cnt_kernel<<<1, 64, 0, stream>>>(cnt);
  moe_gate_kernel<<<NTOK / 4, 256, 0, stream>>>(x, gw, gb, wgt, cnt, meta);
  prefix_kernel<<<1, 64, 0, stream>>>(cnt, base);
  pack_x_kernel<<<NTOK / 2, 256, 0, stream>>>(x, wgt, meta, base, xbf, sortmap);
  zero_out_kernel<<<NTOK / 4, 256, 0, stream>>>(out);       // split-K target

  // GEMM1: r7-proven grid order (np fastest, then m, then e); SPLITK=1
  pack_w_kernel<HDIM, DMODEL><<<dim3(DMODEL / 64, HDIM / 128, NEXP), 256, 0, stream>>>(w1, wp);
  moe_gemm256_kernel<DMODEL / 64, 1, DMODEL, HDIM, true, false, __bf16>
      <<<dim3(HDIM / 256, 40, NEXP), 1024, 0, stream>>>(
          xbf, wp, b1, cnt, base, sortmap, hmat);

  // GEMM2: SPLITK=4 (y = kh*40 + m), atomicAdd into zeroed out
  pack_w_kernel<DMODEL, HDIM><<<dim3(HDIM / 64, DMODEL / 128, NEXP), 256, 0, stream>>>(w2, wp);
  moe_gemm256_kernel<HDIM / 64, 4, HDIM, DMODEL, false, true, float>
      <<<dim3(DMODEL / 256, 4 * 40, NEXP), 1024, 0, stream>>>(
          hmat, wp, b2, cnt, base, sortmap, out);
}

// Round 11
// 466.180 us; speedup vs baseline: 1.2505x; 1.0941x over previous
//
#include <hip/hip_runtime.h>
#include <hip/hip_bf16.h>
#include <stdint.h>

typedef __attribute__((ext_vector_type(8))) __bf16 bf16x8;
typedef __attribute__((ext_vector_type(4))) __bf16 bf16x4;
typedef __attribute__((ext_vector_type(4))) float  f32x4;

#define NTOK   8192
#define DMODEL 1024
#define HDIM   4096
#define NEXP   8

__device__ __forceinline__ void glds16(const void* g, void* l) {
  __builtin_amdgcn_global_load_lds(
      (const __attribute__((address_space(1))) uint32_t*)g,
      (__attribute__((address_space(3))) uint32_t*)l, 16, 0, 0);
}

#define WAITV(N) asm volatile("s_waitcnt vmcnt(" #N ")" ::: "memory")
#define SBAR()  do { __builtin_amdgcn_sched_barrier(0); \
                     __builtin_amdgcn_s_barrier();      \
                     __builtin_amdgcn_sched_barrier(0); } while (0)

// ------------------------------------------------------------------ utils
__global__ void zero_cnt_kernel(int* cnt) {
  if (threadIdx.x < NEXP) cnt[threadIdx.x] = 0;
}

// base[e+1] = base[e] + round256(cnt[e])   (256-row M-tiles)
__global__ void prefix_kernel(const int* __restrict__ cnt, int* __restrict__ base) {
  if (threadIdx.x == 0) {
    int b = 0;
    base[0] = 0;
    for (int e = 0; e < NEXP; ++e) {
      b += (cnt[e] + 255) & ~255;
      base[e + 1] = b;
    }
  }
}

// zero out (atomicAdd target for split-K GEMM2; must run every call since
// the harness does not re-poison between replays)
__global__ __launch_bounds__(256) void zero_out_kernel(float* __restrict__ out) {
  float4 z = {0.f, 0.f, 0.f, 0.f};
  float4* p = (float4*)out + (size_t)blockIdx.x * 1024 + threadIdx.x;
#pragma unroll
  for (int i = 0; i < 4; ++i) p[i * 256] = z;
}

// ------------------------------------------------------------------ gating
__global__ __launch_bounds__(256) void moe_gate_kernel(
    const float* __restrict__ x, const float* __restrict__ gw,
    const float* __restrict__ gb, float* __restrict__ wgt,
    int* __restrict__ cnt, int* __restrict__ meta)
{
  const int lane = threadIdx.x & 63;
  const int wv   = threadIdx.x >> 6;
  const int t    = (blockIdx.x << 2) + wv;
  const float* xp = x + (size_t)t * DMODEL;

  float acc[NEXP];
#pragma unroll
  for (int e = 0; e < NEXP; ++e) acc[e] = 0.f;

#pragma unroll
  for (int j = 0; j < DMODEL / 64; ++j) {
    const int d = (j << 6) + lane;
    const float xv = xp[d];
    const float4 g0 = *(const float4*)(gw + (size_t)d * NEXP);
    const float4 g1 = *(const float4*)(gw + (size_t)d * NEXP + 4);
    acc[0] = fmaf(xv, g0.x, acc[0]);
    acc[1] = fmaf(xv, g0.y, acc[1]);
    acc[2] = fmaf(xv, g0.z, acc[2]);
    acc[3] = fmaf(xv, g0.w, acc[3]);
    acc[4] = fmaf(xv, g1.x, acc[4]);
    acc[5] = fmaf(xv, g1.y, acc[5]);
    acc[6] = fmaf(xv, g1.z, acc[6]);
    acc[7] = fmaf(xv, g1.w, acc[7]);
  }
#pragma unroll
  for (int e = 0; e < NEXP; ++e) {
#pragma unroll
    for (int off = 32; off > 0; off >>= 1)
      acc[e] += __shfl_xor(acc[e], off, 64);
  }
  if (lane == 0) {
    float l[NEXP];
#pragma unroll
    for (int e = 0; e < NEXP; ++e) l[e] = acc[e] + gb[e];
    int i1 = 0; float m1 = l[0];
#pragma unroll
    for (int e = 1; e < NEXP; ++e) if (l[e] > m1) { m1 = l[e]; i1 = e; }
    int i2 = -1; float m2 = -3.402823466e38f;
#pragma unroll
    for (int e = 0; e < NEXP; ++e) if (e != i1 && l[e] > m2) { m2 = l[e]; i2 = e; }
    const int es = i1 > i2 ? i1 : i2;   // reference: last expert in loop wins
    float s = 0.f;
#pragma unroll
    for (int e = 0; e < NEXP; ++e) s += expf(l[e] - m1);
    const float w = expf(l[es] - m1) / s;
    wgt[t] = w;
    const int pos = atomicAdd(&cnt[es], 1);
    meta[t] = (es << 13) | pos;
  }
}

// -------------------------------------------------- pack x (sorted order)
// Pad rows keep stale bytes (finite bf16, harmless): GEMM1 writes 0 to hmat
// pad rows; GEMM2 only scatters gm<ce rows.
__global__ __launch_bounds__(256) void pack_x_kernel(
    const float* __restrict__ x, const float* __restrict__ wgt,
    const int* __restrict__ meta, const int* __restrict__ base,
    __bf16* __restrict__ xbf, int* __restrict__ sortmap)
{
  const int t = blockIdx.x * 2 + (threadIdx.x >> 7);
  const int l = threadIdx.x & 127;
  const int m = meta[t];
  const int es = m >> 13, pos = m & 8191;
  const int dst = base[es] + pos;
  const float w = wgt[t];
  const float4 a = *(const float4*)(x + (size_t)t * DMODEL + l * 8);
  const float4 b = *(const float4*)(x + (size_t)t * DMODEL + l * 8 + 4);
  bf16x8 o;
  o[0] = (__bf16)(a.x * w); o[1] = (__bf16)(a.y * w);
  o[2] = (__bf16)(a.z * w); o[3] = (__bf16)(a.w * w);
  o[4] = (__bf16)(b.x * w); o[5] = (__bf16)(b.y * w);
  o[6] = (__bf16)(b.z * w); o[7] = (__bf16)(b.w * w);
  *(bf16x8*)(xbf + (size_t)dst * DMODEL + l * 8) = o;
  if (l == 0) sortmap[dst] = t;
}

// ------------------------------------------------------------------ pack W
// src [E][K][N] fp32 -> CHUNK-LINEAR bf16 tiles. Tile (e, np, kt) = the
// exact 2048 x 16B staging image of the GEMM's 256-col x 64-k B-tile:
// chunk c (r=c>>3, p=c&7) holds w[kt*64 + (p^(r&7))*8 + j][np*256 + r],
// j=0..7. GEMM B-staging then reads contiguous 16B chunks; pack writes are
// fully coalesced (consecutive threads -> consecutive 16B).
// LDS slab [64 k][257 n] (pad 1): phase-2 gather is 2-way bank-aliased (free).
template<int N, int K>
__global__ __launch_bounds__(256) void pack_w_kernel(
    const float* __restrict__ src, __bf16* __restrict__ dst)
{
  const int kt = blockIdx.x, np = blockIdx.y, e = blockIdx.z;
  const int t = threadIdx.x;
  __shared__ __bf16 sh[64 * 257];

  const float* sp = src + (size_t)e * K * N + (size_t)(kt * 64) * N + np * 256;
  // phase 1: 64k x 256n fp32 slab -> LDS[k][n] bf16 (coalesced global reads)
#pragma unroll
  for (int i = 0; i < 16; ++i) {
    const int id = i * 256 + t;             // 0..4095
    const int k = id >> 6, n4 = id & 63;
    const float4 v = *(const float4*)(sp + (size_t)k * N + n4 * 4);
    __bf16* q = &sh[k * 257 + n4 * 4];
    q[0] = (__bf16)v.x; q[1] = (__bf16)v.y;
    q[2] = (__bf16)v.z; q[3] = (__bf16)v.w;
  }
  __syncthreads();

  // phase 2: emit 2048 chunks, coalesced 16B writes
  __bf16* dbase = dst + (((size_t)e * (N / 256) + np) * (K / 64) + kt) * 16384;
#pragma unroll
  for (int i = 0; i < 8; ++i) {
    const int c = i * 256 + t;
    const int r = c >> 3, p = c & 7;
    const int kk = (p ^ (r & 7)) * 8;
    bf16x8 v;
#pragma unroll
    for (int j = 0; j < 8; ++j) v[j] = sh[(kk + j) * 257 + r];
    *(bf16x8*)(dbase + (size_t)c * 8) = v;
  }
}

// ------------------------------------------------------------------ GEMM
// r7's verified body: 256x256 tile, 8 waves (2M x 4N, wave tile 128x64),
// BK=64, 2-buffer LDS (128KB), per K-tile { WAITV(0); barrier; stage next
// tile into other buffer; compute }. LDS rows 128B, granule phys = q^(row&7),
// A swizzle at glds SOURCE (wave-uniform linear dest, m104 rule); B source
// is CHUNK-LINEAR packed (swizzle baked by pack_w) -> contiguous reads.
// Split-K (GEMM2): kh = blockIdx.y/40, partials atomicAdd into zeroed out,
// bias added by kh==0 only (r9-verified path).
template<int KSTEPS, int SPLITK, int ASTRIDE, int NOUT, bool RELU, bool SCATTER, typename OutT>
__global__ __launch_bounds__(512, 1) void moe_gemm256_kernel(
    const __bf16* __restrict__ Am, const __bf16* __restrict__ Bp,
    const float* __restrict__ bias, const int* __restrict__ cnt,
    const int* __restrict__ base, const int* __restrict__ sortmap,
    OutT* __restrict__ outp)
{
  const int e  = blockIdx.z;
  const int ce = cnt[e];
  const int rb = base[e];
  const int cep = base[e + 1] - rb;        // padded count (multiple of 256)
  const int m  = blockIdx.y % 40;
  const int kh = blockIdx.y / 40;
  const int m0 = m << 8;
  if (m0 >= cep) return;
  const int np = blockIdx.x, n0 = np << 8;

  constexpr int KH = KSTEPS / SPLITK;
  const int ktbase = kh * KH;              // starting K-tile of this chunk

  const int tid = threadIdx.x, lane = tid & 63, wv = tid >> 6;
  const int wm = wv >> 2, wn = wv & 3;     // wave tile: rows wm*128, cols wn*64
  const int rl = lane & 15, sl = lane >> 4;

  __shared__ alignas(16) __bf16 lds[65536];   // 2 buffers x 64KB

  // per-lane staging SOURCES: 4 A + 4 B chunks (16B) per K-tile
  const __bf16* asrc[4];
  const __bf16* bsrc[4];
#pragma unroll
  for (int i = 0; i < 4; ++i) {
    const int c = (wv * 4 + i) * 64 + lane;       // chunk id 0..2047
    const int r = c >> 3, p = c & 7;              // tile row 0..255, granule
    asrc[i] = Am + (size_t)(rb + m0 + r) * ASTRIDE + (p ^ (r & 7)) * 8 + ktbase * 64;
    bsrc[i] = Bp + (((size_t)e * (NOUT / 256) + np) * KSTEPS + ktbase) * 16384
                 + (size_t)c * 8;
  }

  auto stage = [&](int buf, int ks) {
    __bf16* Ad = lds + buf * 32768;               // wave-uniform dests
    __bf16* Bd = Ad + 16384;
#pragma unroll
    for (int i = 0; i < 4; ++i)
      glds16(asrc[i] + ks * 64, Ad + (wv * 4 + i) * 512);
#pragma unroll
    for (int i = 0; i < 4; ++i)
      glds16(bsrc[i] + (size_t)ks * 16384, Bd + (wv * 4 + i) * 512);
  };

  f32x4 acc[8][4] = {};

  stage(0, 0);
  for (int ks = 0; ks < KH; ++ks) {
    const int buf = ks & 1;
    WAITV(0);                    // this K-tile's stages (issued last iter) landed
    SBAR();                      // visible to all waves; prev buf fully read
    if (ks + 1 < KH) stage(buf ^ 1, ks + 1);

    const char* Ab = (const char*)lds + buf * 65536 + wm * 16384;
    const char* Bb = (const char*)lds + buf * 65536 + 32768 + (wn >> 1) * 16384;

#pragma unroll
    for (int kk = 0; kk < 2; ++kk) {
      bf16x8 af[8];
#pragma unroll
      for (int mf = 0; mf < 8; ++mf) {
        const int row = mf * 16 + rl;
        af[mf] = *(const bf16x8*)(Ab + row * 128 + (((kk * 4 + sl) ^ (row & 7)) << 4));
      }
#pragma unroll
      for (int nh = 0; nh < 2; ++nh) {
        bf16x8 bf2[2];
#pragma unroll
        for (int nf2 = 0; nf2 < 2; ++nf2) {
          const int row = (wn & 1) * 64 + nh * 32 + nf2 * 16 + rl;
          bf2[nf2] = *(const bf16x8*)(Bb + row * 128 + (((kk * 4 + sl) ^ (row & 7)) << 4));
        }
        __builtin_amdgcn_s_setprio(1);
#pragma unroll
        for (int mf = 0; mf < 8; ++mf)
#pragma unroll
          for (int nf2 = 0; nf2 < 2; ++nf2)
            acc[mf][nh * 2 + nf2] = __builtin_amdgcn_mfma_f32_16x16x32_bf16(
                af[mf], bf2[nf2], acc[mf][nh * 2 + nf2], 0, 0, 0);
        __builtin_amdgcn_s_setprio(0);
      }
    }
  }

  // epilogue: bias (+relu); sorted write, or token scatter (+split-K atomic)
  float bb[4];
#pragma unroll
  for (int nf = 0; nf < 4; ++nf)
    bb[nf] = bias[(size_t)e * NOUT + n0 + wn * 64 + nf * 16 + rl];

#pragma unroll
  for (int mf = 0; mf < 8; ++mf) {
#pragma unroll
    for (int j = 0; j < 4; ++j) {
      const int gm = m0 + wm * 128 + mf * 16 + sl * 4 + j;
      if constexpr (SCATTER) {
        if (gm < ce) {
          const int tok = sortmap[rb + gm];
          OutT* op = outp + (size_t)tok * NOUT + n0 + wn * 64;
#pragma unroll
          for (int nf = 0; nf < 4; ++nf) {
            float v = acc[mf][nf][j] + ((kh == 0) ? bb[nf] : 0.f);
            if constexpr (SPLITK > 1)
              atomicAdd((float*)&op[nf * 16 + rl], v);
            else
              op[nf * 16 + rl] = (OutT)v;
          }
        }
      } else {
        OutT* op = outp + (size_t)(rb + gm) * NOUT + n0 + wn * 64;
        const bool live = gm < ce;
#pragma unroll
        for (int nf = 0; nf < 4; ++nf) {
          float v = acc[mf][nf][j] + bb[nf];
          if constexpr (RELU) v = fmaxf(v, 0.f);
          op[nf * 16 + rl] = live ? (OutT)v : (OutT)0.f;
        }
      }
    }
  }
}

// ------------------------------------------------------------------ launch
extern "C" void kernel_launch(void* const* d_in, const int* in_sizes, int n_in,
                              void* d_out, int out_size, void* d_ws, size_t ws_size,
                              hipStream_t stream)
{
  const float* x  = (const float*)d_in[0];
  const float* gw = (const float*)d_in[1];
  const float* gb = (const float*)d_in[2];
  const float* w1 = (const float*)d_in[3];
  const float* b1 = (const float*)d_in[4];
  const float* w2 = (const float*)d_in[5];
  const float* b2 = (const float*)d_in[6];
  float* out = (float*)d_out;

  char* ws = (char*)d_ws;
  int*    cnt     = (int*)ws;                               // 32 B
  int*    base    = (int*)(ws + 256);                       // 9 ints
  int*    meta    = (int*)(ws + 4096);                      // 32 KB
  float*  wgt     = (float*)(ws + 40960);                   // 32 KB
  int*    sortmap = (int*)(ws + 81920);                     // 41 KB
  __bf16* xbf     = (__bf16*)(ws + ((size_t)1   << 20));    // <= 20.5 MB (10240 rows)
  __bf16* hmat    = (__bf16*)(ws + ((size_t)22  << 20));    // <= 80 MB   (10240 rows)
  __bf16* wp      = (__bf16*)(ws + ((size_t)104 << 20));    // 64 MB (w1p then w2p)

  zero_cnt_kernel<<<1, 64, 0, stream>>>(cnt);
  moe_gate_kernel<<<NTOK / 4, 256, 0, stream>>>(x, gw, gb, wgt, cnt, meta);
  prefix_kernel<<<1, 64, 0, stream>>>(cnt, base);
  pack_x_kernel<<<NTOK / 2, 256, 0, stream>>>(x, wgt, meta, base, xbf, sortmap);
  zero_out_kernel<<<NTOK / 4, 256, 0, stream>>>(out);       // split-K target

  // GEMM1: grid (np=16, m=40, e=8), SPLITK=1
  pack_w_kernel<HDIM, DMODEL><<<dim3(DMODEL / 64, HDIM / 256, NEXP), 256, 0, stream>>>(w1, wp);
  moe_gemm256_kernel<DMODEL / 64, 1, DMODEL, HDIM, true, false, __bf16>
      <<<dim3(HDIM / 256, 40, NEXP), 512, 0, stream>>>(
          xbf, wp, b1, cnt, base, sortmap, hmat);

  // GEMM2: SPLITK=2 (y = kh*40 + m), atomicAdd into zeroed out
  pack_w_kernel<DMODEL, HDIM><<<dim3(HDIM / 64, DMODEL / 256, NEXP), 256, 0, stream>>>(w2, wp);
  moe_gemm256_kernel<HDIM / 64, 2, HDIM, DMODEL, false, true, float>
      <<<dim3(DMODEL / 256, 2 * 40, NEXP), 512, 0, stream>>>(
          hmat, wp, b2, cnt, base, sortmap, out);
}

// Round 12
// 437.190 us; speedup vs baseline: 1.3334x; 1.0663x over previous
//
#include <hip/hip_runtime.h>
#include <hip/hip_bf16.h>
#include <stdint.h>

typedef __attribute__((ext_vector_type(8))) __bf16 bf16x8;
typedef __attribute__((ext_vector_type(4))) __bf16 bf16x4;
typedef __attribute__((ext_vector_type(4))) float  f32x4;

#define NTOK   8192
#define DMODEL 1024
#define HDIM   4096
#define NEXP   8

__device__ __forceinline__ void glds16(const void* g, void* l) {
  __builtin_amdgcn_global_load_lds(
      (const __attribute__((address_space(1))) uint32_t*)g,
      (__attribute__((address_space(3))) uint32_t*)l, 16, 0, 0);
}

#define WAITV(N) asm volatile("s_waitcnt vmcnt(" #N ")" ::: "memory")
#define SBAR()  do { __builtin_amdgcn_sched_barrier(0); \
                     __builtin_amdgcn_s_barrier();      \
                     __builtin_amdgcn_sched_barrier(0); } while (0)

// ------------------------------------------------------------------ utils
__global__ void zero_cnt_kernel(int* cnt) {
  if (threadIdx.x < NEXP) cnt[threadIdx.x] = 0;
}

// base[e+1] = base[e] + round128(cnt[e])   (128-row M-tiles)
__global__ void prefix_kernel(const int* __restrict__ cnt, int* __restrict__ base) {
  if (threadIdx.x == 0) {
    int b = 0;
    base[0] = 0;
    for (int e = 0; e < NEXP; ++e) {
      b += (cnt[e] + 127) & ~127;
      base[e + 1] = b;
    }
  }
}

// ------------------------------------------------------------------ gating
__global__ __launch_bounds__(256) void moe_gate_kernel(
    const float* __restrict__ x, const float* __restrict__ gw,
    const float* __restrict__ gb, float* __restrict__ wgt,
    int* __restrict__ cnt, int* __restrict__ meta)
{
  const int lane = threadIdx.x & 63;
  const int wv   = threadIdx.x >> 6;
  const int t    = (blockIdx.x << 2) + wv;
  const float* xp = x + (size_t)t * DMODEL;

  float acc[NEXP];
#pragma unroll
  for (int e = 0; e < NEXP; ++e) acc[e] = 0.f;

#pragma unroll
  for (int j = 0; j < DMODEL / 64; ++j) {
    const int d = (j << 6) + lane;
    const float xv = xp[d];
    const float4 g0 = *(const float4*)(gw + (size_t)d * NEXP);
    const float4 g1 = *(const float4*)(gw + (size_t)d * NEXP + 4);
    acc[0] = fmaf(xv, g0.x, acc[0]);
    acc[1] = fmaf(xv, g0.y, acc[1]);
    acc[2] = fmaf(xv, g0.z, acc[2]);
    acc[3] = fmaf(xv, g0.w, acc[3]);
    acc[4] = fmaf(xv, g1.x, acc[4]);
    acc[5] = fmaf(xv, g1.y, acc[5]);
    acc[6] = fmaf(xv, g1.z, acc[6]);
    acc[7] = fmaf(xv, g1.w, acc[7]);
  }
#pragma unroll
  for (int e = 0; e < NEXP; ++e) {
#pragma unroll
    for (int off = 32; off > 0; off >>= 1)
      acc[e] += __shfl_xor(acc[e], off, 64);
  }
  if (lane == 0) {
    float l[NEXP];
#pragma unroll
    for (int e = 0; e < NEXP; ++e) l[e] = acc[e] + gb[e];
    int i1 = 0; float m1 = l[0];
#pragma unroll
    for (int e = 1; e < NEXP; ++e) if (l[e] > m1) { m1 = l[e]; i1 = e; }
    int i2 = -1; float m2 = -3.402823466e38f;
#pragma unroll
    for (int e = 0; e < NEXP; ++e) if (e != i1 && l[e] > m2) { m2 = l[e]; i2 = e; }
    const int es = i1 > i2 ? i1 : i2;   // reference: last expert in loop wins
    float s = 0.f;
#pragma unroll
    for (int e = 0; e < NEXP; ++e) s += expf(l[e] - m1);
    const float w = expf(l[es] - m1) / s;
    wgt[t] = w;
    const int pos = atomicAdd(&cnt[es], 1);
    meta[t] = (es << 13) | pos;
  }
}

// -------------------------------------------------- pack x (sorted order)
// Pad rows keep stale bytes (finite bf16, harmless): GEMM1 writes 0 to hmat
// pad rows; GEMM2 only scatters gm<ce rows.
__global__ __launch_bounds__(256) void pack_x_kernel(
    const float* __restrict__ x, const float* __restrict__ wgt,
    const int* __restrict__ meta, const int* __restrict__ base,
    __bf16* __restrict__ xbf, int* __restrict__ sortmap)
{
  const int t = blockIdx.x * 2 + (threadIdx.x >> 7);
  const int l = threadIdx.x & 127;
  const int m = meta[t];
  const int es = m >> 13, pos = m & 8191;
  const int dst = base[es] + pos;
  const float w = wgt[t];
  const float4 a = *(const float4*)(x + (size_t)t * DMODEL + l * 8);
  const float4 b = *(const float4*)(x + (size_t)t * DMODEL + l * 8 + 4);
  bf16x8 o;
  o[0] = (__bf16)(a.x * w); o[1] = (__bf16)(a.y * w);
  o[2] = (__bf16)(a.z * w); o[3] = (__bf16)(a.w * w);
  o[4] = (__bf16)(b.x * w); o[5] = (__bf16)(b.y * w);
  o[6] = (__bf16)(b.z * w); o[7] = (__bf16)(b.w * w);
  *(bf16x8*)(xbf + (size_t)dst * DMODEL + l * 8) = o;
  if (l == 0) sortmap[dst] = t;
}

// ------------------------------------------------------------------ pack W
// src [E][K][N] fp32 -> CHUNK-LINEAR bf16 tiles (r11-verified). Tile
// (e, np, kt) = 2048 x 16B chunks; chunk c (r=c>>3, p=c&7) holds
// w[kt*64 + (p^(r&7))*8 + j][np*256 + r], j=0..7.
template<int N, int K>
__global__ __launch_bounds__(256) void pack_w_kernel(
    const float* __restrict__ src, __bf16* __restrict__ dst)
{
  const int kt = blockIdx.x, np = blockIdx.y, e = blockIdx.z;
  const int t = threadIdx.x;
  __shared__ __bf16 sh[64 * 257];

  const float* sp = src + (size_t)e * K * N + (size_t)(kt * 64) * N + np * 256;
#pragma unroll
  for (int i = 0; i < 16; ++i) {
    const int id = i * 256 + t;             // 0..4095
    const int k = id >> 6, n4 = id & 63;
    const float4 v = *(const float4*)(sp + (size_t)k * N + n4 * 4);
    __bf16* q = &sh[k * 257 + n4 * 4];
    q[0] = (__bf16)v.x; q[1] = (__bf16)v.y;
    q[2] = (__bf16)v.z; q[3] = (__bf16)v.w;
  }
  __syncthreads();

  __bf16* dbase = dst + (((size_t)e * (N / 256) + np) * (K / 64) + kt) * 16384;
#pragma unroll
  for (int i = 0; i < 8; ++i) {
    const int c = i * 256 + t;
    const int r = c >> 3, p = c & 7;
    const int kk = (p ^ (r & 7)) * 8;
    bf16x8 v;
#pragma unroll
    for (int j = 0; j < 8; ++j) v[j] = sh[(kk + j) * 257 + r];
    *(bf16x8*)(dbase + (size_t)c * 8) = v;
  }
}

// ------------------------------------------------------------------ GEMM
// PERSISTENT grouped GEMM, 128x256 tile, 8 waves (2M x 4N, wave tile 64x64),
// BK=64. LDS: RING OF 3 x (A 16KB | B 32KB) = 144KB -> true counted-vmcnt
// boundary: stage(t+2) issued during compute(t); at tile boundary WAITV(6)
// leaves only the newest tile's 6 loads in flight (oldest tile proven
// landed). stage(t+2) writes buf((t+2)%3) = buf(t-1), whose readers all
// passed the barrier at t's start -> race-free. One barrier per K-tile.
// LDS rows 128B, granule phys = q^(row&7); A swizzle at glds SOURCE
// (wave-uniform linear dest, m104 rule); B chunk-linear packed.
// Work list: persistent 256 blocks walk (e, m, np) np-fastest (A-tile
// shared by consecutive items).
template<int KT, int ASTRIDE, int NOUT, int NPB, bool RELU, bool SCATTER, typename OutT>
__global__ __launch_bounds__(512, 1) void moe_gemm_persist_kernel(
    const __bf16* __restrict__ Am, const __bf16* __restrict__ Bp,
    const float* __restrict__ bias, const int* __restrict__ cnt,
    const int* __restrict__ base, const int* __restrict__ sortmap,
    OutT* __restrict__ outp)
{
  const int tid = threadIdx.x, lane = tid & 63, wv = tid >> 6;
  const int wm = wv >> 2, wn = wv & 3;     // wave tile: rows wm*64, cols wn*64
  const int rl = lane & 15, sl = lane >> 4;

  __shared__ alignas(16) __bf16 lds[73728];   // 3 bufs x 24576 elems (48KB)

  int wi = blockIdx.x;
  for (;;) {
    // ---- decode work item wi -> (e, m, np), np-fastest
    int e = -1, m = 0, np = 0, acct = 0;
#pragma unroll
    for (int ee = 0; ee < NEXP; ++ee) {
      const int mte = (base[ee + 1] - base[ee]) >> 7;
      const int we = mte * NPB;
      if (e < 0 && wi < acct + we) {
        const int l = wi - acct;
        e = ee; m = l / NPB; np = l % NPB;
      }
      acct += we;
    }
    if (e < 0) break;                      // past end of work list

    const int ce = cnt[e];
    const int rb = base[e];
    const int m0 = m << 7;
    const int n0 = np << 8;

    // per-item staging sources
    const __bf16* asrc[2];                 // A: 1024 chunks, 2 groups/thread
#pragma unroll
    for (int i = 0; i < 2; ++i) {
      const int c = (wv * 2 + i) * 64 + lane;     // 0..1023
      const int r = c >> 3, p = c & 7;            // row 0..127
      asrc[i] = Am + (size_t)(rb + m0 + r) * ASTRIDE + (p ^ (r & 7)) * 8;
    }
    const __bf16* bsrc[4];                 // B: 2048 chunks, 4 groups/thread
    const __bf16* btile = Bp + ((size_t)(e * (NOUT / 256) + np)) * (size_t)KT * 16384;
#pragma unroll
    for (int i = 0; i < 4; ++i) {
      const int c = (wv * 4 + i) * 64 + lane;     // 0..2047
      bsrc[i] = btile + (size_t)c * 8;
    }

    auto stage = [&](int buf, int ks) {
      __bf16* Ad = lds + buf * 24576;             // wave-uniform dests
      __bf16* Bd = Ad + 8192;
#pragma unroll
      for (int i = 0; i < 2; ++i)
        glds16(asrc[i] + ks * 64, Ad + (wv * 2 + i) * 512);
#pragma unroll
      for (int i = 0; i < 4; ++i)
        glds16(bsrc[i] + (size_t)ks * 16384, Bd + (wv * 4 + i) * 512);
    };

    f32x4 acc[4][4] = {};

    auto compute = [&](int buf) {
      const char* Ab = (const char*)(lds + buf * 24576);
      const char* Bb = Ab + 16384;
#pragma unroll
      for (int kk = 0; kk < 2; ++kk) {
        bf16x8 af[4], bf2[4];
#pragma unroll
        for (int mf = 0; mf < 4; ++mf) {
          const int row = wm * 64 + mf * 16 + rl;         // 0..127
          af[mf] = *(const bf16x8*)(Ab + row * 128 + (((kk * 4 + sl) ^ (row & 7)) << 4));
        }
#pragma unroll
        for (int nf = 0; nf < 4; ++nf) {
          const int row = wn * 64 + nf * 16 + rl;         // 0..255
          bf2[nf] = *(const bf16x8*)(Bb + row * 128 + (((kk * 4 + sl) ^ (row & 7)) << 4));
        }
        __builtin_amdgcn_s_setprio(1);
#pragma unroll
        for (int mf = 0; mf < 4; ++mf)
#pragma unroll
          for (int nf = 0; nf < 4; ++nf)
            acc[mf][nf] = __builtin_amdgcn_mfma_f32_16x16x32_bf16(
                af[mf], bf2[nf], acc[mf][nf], 0, 0, 0);
        __builtin_amdgcn_s_setprio(0);
      }
    };

    // ---- pipeline: 3-buf ring, depth 2, counted vmcnt(6)
    WAITV(0);                  // reset vmem counting (epilogue/bias of prev item)
    SBAR();                    // prev item's LDS readers done before overwrite
    stage(0, 0);
    stage(1, 1);
    for (int ks = 0; ks < KT; ++ks) {
      if (ks + 1 < KT) { WAITV(6); }       // tile ks landed; ks+1's 6 in flight
      else            { WAITV(0); }
      SBAR();                              // all waves see tile ks staged
      if (ks + 2 < KT) stage((ks + 2) % 3, ks + 2);   // overwrites buf(ks-1)
      compute(ks % 3);
    }

    // ---- epilogue: bias (+relu); sorted write or token scatter
    float bb[4];
#pragma unroll
    for (int nf = 0; nf < 4; ++nf)
      bb[nf] = bias[(size_t)e * NOUT + n0 + wn * 64 + nf * 16 + rl];

#pragma unroll
    for (int mf = 0; mf < 4; ++mf) {
#pragma unroll
      for (int j = 0; j < 4; ++j) {
        const int gm = m0 + wm * 64 + mf * 16 + sl * 4 + j;
        if constexpr (SCATTER) {
          if (gm < ce) {
            const int tok = sortmap[rb + gm];
            OutT* op = outp + (size_t)tok * NOUT + n0 + wn * 64;
#pragma unroll
            for (int nf = 0; nf < 4; ++nf)
              op[nf * 16 + rl] = (OutT)(acc[mf][nf][j] + bb[nf]);
          }
        } else {
          OutT* op = outp + (size_t)(rb + gm) * NOUT + n0 + wn * 64;
          const bool live = gm < ce;
#pragma unroll
          for (int nf = 0; nf < 4; ++nf) {
            float v = acc[mf][nf][j] + bb[nf];
            if constexpr (RELU) v = fmaxf(v, 0.f);
            op[nf * 16 + rl] = live ? (OutT)v : (OutT)0.f;
          }
        }
      }
    }

    wi += gridDim.x;
  }
}

// ------------------------------------------------------------------ launch
extern "C" void kernel_launch(void* const* d_in, const int* in_sizes, int n_in,
                              void* d_out, int out_size, void* d_ws, size_t ws_size,
                              hipStream_t stream)
{
  const float* x  = (const float*)d_in[0];
  const float* gw = (const float*)d_in[1];
  const float* gb = (const float*)d_in[2];
  const float* w1 = (const float*)d_in[3];
  const float* b1 = (const float*)d_in[4];
  const float* w2 = (const float*)d_in[5];
  const float* b2 = (const float*)d_in[6];
  float* out = (float*)d_out;

  char* ws = (char*)d_ws;
  int*    cnt     = (int*)ws;                               // 32 B
  int*    base    = (int*)(ws + 256);                       // 9 ints
  int*    meta    = (int*)(ws + 4096);                      // 32 KB
  float*  wgt     = (float*)(ws + 40960);                   // 32 KB
  int*    sortmap = (int*)(ws + 81920);                     // 41 KB
  __bf16* xbf     = (__bf16*)(ws + ((size_t)1   << 20));    // <= 18.5 MB (9216 rows)
  __bf16* hmat    = (__bf16*)(ws + ((size_t)22  << 20));    // <= 72 MB   (9216 rows)
  __bf16* wp      = (__bf16*)(ws + ((size_t)104 << 20));    // 64 MB (w1p then w2p)

  zero_cnt_kernel<<<1, 64, 0, stream>>>(cnt);
  moe_gate_kernel<<<NTOK / 4, 256, 0, stream>>>(x, gw, gb, wgt, cnt, meta);
  prefix_kernel<<<1, 64, 0, stream>>>(cnt, base);
  pack_x_kernel<<<NTOK / 2, 256, 0, stream>>>(x, wgt, meta, base, xbf, sortmap);

  // GEMM1: persistent 256 blocks, work = Sum_e mtiles(e) * 16 (~1088)
  pack_w_kernel<HDIM, DMODEL><<<dim3(DMODEL / 64, HDIM / 256, NEXP), 256, 0, stream>>>(w1, wp);
  moe_gemm_persist_kernel<DMODEL / 64, DMODEL, HDIM, HDIM / 256, true, false, __bf16>
      <<<256, 512, 0, stream>>>(xbf, wp, b1, cnt, base, sortmap, hmat);

  // GEMM2: persistent 256 blocks, work = Sum_e mtiles(e) * 4 (~272)
  pack_w_kernel<DMODEL, HDIM><<<dim3(HDIM / 64, DMODEL / 256, NEXP), 256, 0, stream>>>(w2, wp);
  moe_gemm_persist_kernel<HDIM / 64, HDIM, DMODEL, DMODEL / 256, false, true, float>
      <<<256, 512, 0, stream>>>(hmat, wp, b2, cnt, base, sortmap, out);
}

// Round 13
// 395.356 us; speedup vs baseline: 1.4745x; 1.1058x over previous
//
#include <hip/hip_runtime.h>
#include <hip/hip_bf16.h>
#include <stdint.h>

typedef __attribute__((ext_vector_type(8))) __bf16 bf16x8;
typedef __attribute__((ext_vector_type(4))) __bf16 bf16x4;
typedef __attribute__((ext_vector_type(4))) float  f32x4;

#define NTOK   8192
#define DMODEL 1024
#define HDIM   4096
#define NEXP   8

__device__ __forceinline__ void glds16(const void* g, void* l) {
  __builtin_amdgcn_global_load_lds(
      (const __attribute__((address_space(1))) uint32_t*)g,
      (__attribute__((address_space(3))) uint32_t*)l, 16, 0, 0);
}

#define WAITV(N) asm volatile("s_waitcnt vmcnt(" #N ")" ::: "memory")
#define SBAR()  do { __builtin_amdgcn_sched_barrier(0); \
                     __builtin_amdgcn_s_barrier();      \
                     __builtin_amdgcn_sched_barrier(0); } while (0)

// ------------------------------------------------------------------ utils
__global__ void zero_cnt_kernel(int* cnt) {
  if (threadIdx.x < NEXP) cnt[threadIdx.x] = 0;
}

// base[e+1] = base[e] + round256(cnt[e])   (256-row M-tiles)
__global__ void prefix_kernel(const int* __restrict__ cnt, int* __restrict__ base) {
  if (threadIdx.x == 0) {
    int b = 0;
    base[0] = 0;
    for (int e = 0; e < NEXP; ++e) {
      b += (cnt[e] + 255) & ~255;
      base[e + 1] = b;
    }
  }
}

// ------------------------------------------------------------------ bodies
__device__ void gate_body(int bid,
    const float* __restrict__ x, const float* __restrict__ gw,
    const float* __restrict__ gb, float* __restrict__ wgt,
    int* __restrict__ cnt, int* __restrict__ meta)
{
  const int lane = threadIdx.x & 63;
  const int wv   = threadIdx.x >> 6;
  const int t    = (bid << 2) + wv;
  const float* xp = x + (size_t)t * DMODEL;

  float acc[NEXP];
#pragma unroll
  for (int e = 0; e < NEXP; ++e) acc[e] = 0.f;

#pragma unroll
  for (int j = 0; j < DMODEL / 64; ++j) {
    const int d = (j << 6) + lane;
    const float xv = xp[d];
    const float4 g0 = *(const float4*)(gw + (size_t)d * NEXP);
    const float4 g1 = *(const float4*)(gw + (size_t)d * NEXP + 4);
    acc[0] = fmaf(xv, g0.x, acc[0]);
    acc[1] = fmaf(xv, g0.y, acc[1]);
    acc[2] = fmaf(xv, g0.z, acc[2]);
    acc[3] = fmaf(xv, g0.w, acc[3]);
    acc[4] = fmaf(xv, g1.x, acc[4]);
    acc[5] = fmaf(xv, g1.y, acc[5]);
    acc[6] = fmaf(xv, g1.z, acc[6]);
    acc[7] = fmaf(xv, g1.w, acc[7]);
  }
#pragma unroll
  for (int e = 0; e < NEXP; ++e) {
#pragma unroll
    for (int off = 32; off > 0; off >>= 1)
      acc[e] += __shfl_xor(acc[e], off, 64);
  }
  if (lane == 0) {
    float l[NEXP];
#pragma unroll
    for (int e = 0; e < NEXP; ++e) l[e] = acc[e] + gb[e];
    int i1 = 0; float m1 = l[0];
#pragma unroll
    for (int e = 1; e < NEXP; ++e) if (l[e] > m1) { m1 = l[e]; i1 = e; }
    int i2 = -1; float m2 = -3.402823466e38f;
#pragma unroll
    for (int e = 0; e < NEXP; ++e) if (e != i1 && l[e] > m2) { m2 = l[e]; i2 = e; }
    const int es = i1 > i2 ? i1 : i2;   // reference: last expert in loop wins
    float s = 0.f;
#pragma unroll
    for (int e = 0; e < NEXP; ++e) s += expf(l[e] - m1);
    const float w = expf(l[es] - m1) / s;
    wgt[t] = w;
    const int pos = atomicAdd(&cnt[es], 1);
    meta[t] = (es << 13) | pos;
  }
}

// r5/r7-verified pack_w body: src [E][K][N] fp32 -> dst [E][N/128][128 n][K]
// bf16 (k-contig rows; GEMM applies LDS swizzle at glds-source time).
template<int N, int K>
__device__ void packw_body(int bid, const float* __restrict__ src,
                           __bf16* __restrict__ dst)
{
  const int KT = K / 64, NP = N / 128;
  const int kt = bid % KT, np = (bid / KT) % NP, e = bid / (KT * NP);
  const int k0 = kt * 64;
  const int t = threadIdx.x;
  __shared__ __bf16 sh[8192];   // 64 k x 128 n, n4 XOR-swizzled by (k&3)

  const float* sp = src + (size_t)e * K * N + (size_t)k0 * N + np * 128;
#pragma unroll
  for (int i = 0; i < 8; ++i) {
    const int id = i * 256 + t;
    const int k = id >> 5, n4 = id & 31;
    const float4 v = *(const float4*)(sp + (size_t)k * N + n4 * 4);
    const int phys = n4 ^ ((k & 3) << 3);
    bf16x4 o; o[0] = (__bf16)v.x; o[1] = (__bf16)v.y;
              o[2] = (__bf16)v.z; o[3] = (__bf16)v.w;
    *(bf16x4*)&sh[k * 128 + phys * 4] = o;
  }
  __syncthreads();

  __bf16* dbase = dst + ((size_t)(e * NP + np) * 128) * K + k0;
#pragma unroll
  for (int j2 = 0; j2 < 4; ++j2) {
    const int c = j2 * 256 + t;
    const int n = c >> 3, ks8 = c & 7;
    bf16x8 v;
#pragma unroll
    for (int j = 0; j < 8; ++j) {
      const int k = ks8 * 8 + j;
      v[j] = sh[k * 128 + (((n >> 2) ^ ((k & 3) << 3)) << 2) + (n & 3)];
    }
    *(bf16x8*)(dbase + (size_t)n * K + ks8 * 8) = v;
  }
}

// fused A: gate (2048 blocks) + pack_w1 (4096) [+ pack_w2 (4096)]
__global__ __launch_bounds__(256) void fusedA_kernel(
    const float* __restrict__ x, const float* __restrict__ gw,
    const float* __restrict__ gb, float* __restrict__ wgt,
    int* __restrict__ cnt, int* __restrict__ meta,
    const float* __restrict__ w1, __bf16* __restrict__ w1p,
    const float* __restrict__ w2, __bf16* __restrict__ w2p)
{
  const int b = blockIdx.x;
  if (b < 2048)       gate_body(b, x, gw, gb, wgt, cnt, meta);
  else if (b < 6144)  packw_body<HDIM, DMODEL>(b - 2048, w1, w1p);
  else                packw_body<DMODEL, HDIM>(b - 6144, w2, w2p);
}

// standalone pack_w (serial fallback for w2)
template<int N, int K>
__global__ __launch_bounds__(256) void pack_w_kernel(
    const float* __restrict__ src, __bf16* __restrict__ dst)
{
  packw_body<N, K>(blockIdx.x, src, dst);
}

// -------------------------------------------------- pack x (sorted order)
// Pad rows keep stale bytes (finite bf16, harmless): GEMM1 writes 0 to hmat
// pad rows; GEMM2 only scatters gm<ce rows.
__global__ __launch_bounds__(256) void pack_x_kernel(
    const float* __restrict__ x, const float* __restrict__ wgt,
    const int* __restrict__ meta, const int* __restrict__ base,
    __bf16* __restrict__ xbf, int* __restrict__ sortmap)
{
  const int t = blockIdx.x * 2 + (threadIdx.x >> 7);
  const int l = threadIdx.x & 127;
  const int m = meta[t];
  const int es = m >> 13, pos = m & 8191;
  const int dst = base[es] + pos;
  const float w = wgt[t];
  const float4 a = *(const float4*)(x + (size_t)t * DMODEL + l * 8);
  const float4 b = *(const float4*)(x + (size_t)t * DMODEL + l * 8 + 4);
  bf16x8 o;
  o[0] = (__bf16)(a.x * w); o[1] = (__bf16)(a.y * w);
  o[2] = (__bf16)(a.z * w); o[3] = (__bf16)(a.w * w);
  o[4] = (__bf16)(b.x * w); o[5] = (__bf16)(b.y * w);
  o[6] = (__bf16)(b.z * w); o[7] = (__bf16)(b.w * w);
  *(bf16x8*)(xbf + (size_t)dst * DMODEL + l * 8) = o;
  if (l == 0) sortmap[dst] = t;
}

// ------------------------------------------------------------------ GEMM
// r7's verified core (measured 130us/GEMM): 256x256 tile, 8 waves (2M x 4N,
// wave tile 128x64), BK=64, 2-buffer LDS (128KB), per K-tile { WAITV(0);
// barrier; stage next tile into other buffer; compute }. LDS rows 128B,
// granule phys = q^(row&7), swizzle at glds SOURCE (wave-uniform linear
// dest, m104 rule). Grid (np, m, e).
template<int KSTEPS, int ASTRIDE, int NOUT, bool RELU, bool SCATTER, typename OutT>
__global__ __launch_bounds__(512, 1) void moe_gemm256_kernel(
    const __bf16* __restrict__ Am, const __bf16* __restrict__ Bp,
    const float* __restrict__ bias, const int* __restrict__ cnt,
    const int* __restrict__ base, const int* __restrict__ sortmap,
    OutT* __restrict__ outp)
{
  const int e  = blockIdx.z;
  const int ce = cnt[e];
  const int rb = base[e];
  const int cep = base[e + 1] - rb;        // padded count (multiple of 256)
  const int m0 = blockIdx.y << 8;
  if (m0 >= cep) return;
  const int np = blockIdx.x, n0 = np << 8;

  const int tid = threadIdx.x, lane = tid & 63, wv = tid >> 6;
  const int wm = wv >> 2, wn = wv & 3;     // wave tile: rows wm*128, cols wn*64
  const int rl = lane & 15, sl = lane >> 4;

  __shared__ alignas(16) __bf16 lds[65536];   // 2 buffers x 64KB

  // per-lane staging SOURCES: 4 A + 4 B chunks (16B) per K-tile
  const __bf16* asrc[4];
  const __bf16* bsrc[4];
#pragma unroll
  for (int i = 0; i < 4; ++i) {
    const int c = (wv * 4 + i) * 64 + lane;       // chunk id 0..2047
    const int r = c >> 3, p = c & 7;              // tile row 0..255, granule
    const int koff = (p ^ (r & 7)) * 8;
    asrc[i] = Am + (size_t)(rb + m0 + r) * ASTRIDE + koff;
    bsrc[i] = Bp + ((size_t)(e * (NOUT / 128) + np * 2) * 128 + r) * ASTRIDE + koff;
  }

  auto stage = [&](int buf, int ks) {
    __bf16* Ad = lds + buf * 32768;               // wave-uniform dests
    __bf16* Bd = Ad + 16384;
#pragma unroll
    for (int i = 0; i < 4; ++i)
      glds16(asrc[i] + ks * 64, Ad + (wv * 4 + i) * 512);
#pragma unroll
    for (int i = 0; i < 4; ++i)
      glds16(bsrc[i] + ks * 64, Bd + (wv * 4 + i) * 512);
  };

  f32x4 acc[8][4] = {};

  stage(0, 0);
  for (int ks = 0; ks < KSTEPS; ++ks) {
    const int buf = ks & 1;
    WAITV(0);                    // this K-tile's stages (issued last iter) landed
    SBAR();                      // visible to all waves; prev buf fully read
    if (ks + 1 < KSTEPS) stage(buf ^ 1, ks + 1);

    const char* Ab = (const char*)lds + buf * 65536 + wm * 16384;
    const char* Bb = (const char*)lds + buf * 65536 + 32768 + (wn >> 1) * 16384;

#pragma unroll
    for (int kk = 0; kk < 2; ++kk) {
      bf16x8 af[8];
#pragma unroll
      for (int mf = 0; mf < 8; ++mf) {
        const int row = mf * 16 + rl;
        af[mf] = *(const bf16x8*)(Ab + row * 128 + (((kk * 4 + sl) ^ (row & 7)) << 4));
      }
#pragma unroll
      for (int nh = 0; nh < 2; ++nh) {
        bf16x8 bf2[2];
#pragma unroll
        for (int nf2 = 0; nf2 < 2; ++nf2) {
          const int row = (wn & 1) * 64 + nh * 32 + nf2 * 16 + rl;
          bf2[nf2] = *(const bf16x8*)(Bb + row * 128 + (((kk * 4 + sl) ^ (row & 7)) << 4));
        }
        __builtin_amdgcn_s_setprio(1);
#pragma unroll
        for (int mf = 0; mf < 8; ++mf)
#pragma unroll
          for (int nf2 = 0; nf2 < 2; ++nf2)
            acc[mf][nh * 2 + nf2] = __builtin_amdgcn_mfma_f32_16x16x32_bf16(
                af[mf], bf2[nf2], acc[mf][nh * 2 + nf2], 0, 0, 0);
        __builtin_amdgcn_s_setprio(0);
      }
    }
  }

  // epilogue: bias (+relu); sorted write or token scatter
  float bb[4];
#pragma unroll
  for (int nf = 0; nf < 4; ++nf)
    bb[nf] = bias[(size_t)e * NOUT + n0 + wn * 64 + nf * 16 + rl];

#pragma unroll
  for (int mf = 0; mf < 8; ++mf) {
#pragma unroll
    for (int j = 0; j < 4; ++j) {
      const int gm = m0 + wm * 128 + mf * 16 + sl * 4 + j;
      if constexpr (SCATTER) {
        if (gm < ce) {
          const int tok = sortmap[rb + gm];
          OutT* op = outp + (size_t)tok * NOUT + n0 + wn * 64;
#pragma unroll
          for (int nf = 0; nf < 4; ++nf)
            op[nf * 16 + rl] = (OutT)(acc[mf][nf][j] + bb[nf]);
        }
      } else {
        OutT* op = outp + (size_t)(rb + gm) * NOUT + n0 + wn * 64;
        const bool live = gm < ce;
#pragma unroll
        for (int nf = 0; nf < 4; ++nf) {
          float v = acc[mf][nf][j] + bb[nf];
          if constexpr (RELU) v = fmaxf(v, 0.f);
          op[nf * 16 + rl] = live ? (OutT)v : (OutT)0.f;
        }
      }
    }
  }
}

// ------------------------------------------------------------------ launch
extern "C" void kernel_launch(void* const* d_in, const int* in_sizes, int n_in,
                              void* d_out, int out_size, void* d_ws, size_t ws_size,
                              hipStream_t stream)
{
  const float* x  = (const float*)d_in[0];
  const float* gw = (const float*)d_in[1];
  const float* gb = (const float*)d_in[2];
  const float* w1 = (const float*)d_in[3];
  const float* b1 = (const float*)d_in[4];
  const float* w2 = (const float*)d_in[5];
  const float* b2 = (const float*)d_in[6];
  float* out = (float*)d_out;

  char* ws = (char*)d_ws;
  int*    cnt     = (int*)ws;                               // 32 B
  int*    base    = (int*)(ws + 256);                       // 9 ints
  int*    meta    = (int*)(ws + 4096);                      // 32 KB
  float*  wgt     = (float*)(ws + 40960);                   // 32 KB
  int*    sortmap = (int*)(ws + 81920);                     // 41 KB
  __bf16* xbf     = (__bf16*)(ws + ((size_t)1   << 20));    // <= 21 MB (10232 rows)
  __bf16* hmat    = (__bf16*)(ws + ((size_t)22  << 20));    // <= 84 MB
  __bf16* w1p     = (__bf16*)(ws + ((size_t)106 << 20));    // 64 MB

  const bool conc = ws_size >= ((size_t)235 << 20);

  zero_cnt_kernel<<<1, 64, 0, stream>>>(cnt);

  if (conc) {
    __bf16* w2p = (__bf16*)(ws + ((size_t)170 << 20));      // 64 MB (ends 234)
    // gate + pack_w1 + pack_w2 co-scheduled (independent streams of work)
    fusedA_kernel<<<10240, 256, 0, stream>>>(
        x, gw, gb, wgt, cnt, meta, w1, w1p, w2, w2p);
    prefix_kernel<<<1, 64, 0, stream>>>(cnt, base);
    pack_x_kernel<<<NTOK / 2, 256, 0, stream>>>(x, wgt, meta, base, xbf, sortmap);
    moe_gemm256_kernel<DMODEL / 64, DMODEL, HDIM, true, false, __bf16>
        <<<dim3(HDIM / 256, 40, NEXP), 512, 0, stream>>>(
            xbf, w1p, b1, cnt, base, sortmap, hmat);
    moe_gemm256_kernel<HDIM / 64, HDIM, DMODEL, false, true, float>
        <<<dim3(DMODEL / 256, 40, NEXP), 512, 0, stream>>>(
            hmat, w2p, b2, cnt, base, sortmap, out);
  } else {
    // serial fallback (r7 flow): pack w2 into w1p's space after GEMM1
    fusedA_kernel<<<6144, 256, 0, stream>>>(
        x, gw, gb, wgt, cnt, meta, w1, w1p, w2, w1p /*unused*/);
    prefix_kernel<<<1, 64, 0, stream>>>(cnt, base);
    pack_x_kernel<<<NTOK / 2, 256, 0, stream>>>(x, wgt, meta, base, xbf, sortmap);
    moe_gemm256_kernel<DMODEL / 64, DMODEL, HDIM, true, false, __bf16>
        <<<dim3(HDIM / 256, 40, NEXP), 512, 0, stream>>>(
            xbf, w1p, b1, cnt, base, sortmap, hmat);
    pack_w_kernel<DMODEL, HDIM><<<2048, 256, 0, stream>>>(w2, w1p);
    moe_gemm256_kernel<HDIM / 64, HDIM, DMODEL, false, true, float>
        <<<dim3(DMODEL / 256, 40, NEXP), 512, 0, stream>>>(
            hmat, w1p, b2, cnt, base, sortmap, out);
  }
}